// Round 6
// baseline (2730.908 us; speedup 1.0000x reference)
//
#include <hip/hip_runtime.h>
#include <cstdint>
#include <cstddef>

#define T_LEN 2048
#define B_SZ  256
#define H_SZ  64

typedef float v2f __attribute__((ext_vector_type(2)));
typedef unsigned short ushort_t;

__device__ __forceinline__ v2f v2fma(v2f a, v2f b, v2f c) {
#if __has_builtin(__builtin_elementwise_fma)
    return __builtin_elementwise_fma(a, b, c);
#else
    v2f r; r.x = fmaf(a.x, b.x, c.x); r.y = fmaf(a.y, b.y, c.y); return r;
#endif
}

__device__ __forceinline__ float sigmf(float x) {
    return 1.0f / (1.0f + __expf(-x));
}
__device__ __forceinline__ float tanhf_fast(float x) {
    // tanh(x) = 1 - 2/(exp(2x)+1); saturates correctly at +-inf
    return 1.0f - 2.0f / (__expf(2.0f * x) + 1.0f);
}

// fp32 -> bf16 with round-to-nearest-even (values here are finite & bounded)
__device__ __forceinline__ ushort_t f2bf(float f) {
    unsigned int u = __float_as_uint(f);
    u += 0x7fffu + ((u >> 16) & 1u);
    return (ushort_t)(u >> 16);
}
__device__ __forceinline__ float bf_lo(unsigned int u) {   // low bf16 of a dword
    return __uint_as_float(u << 16);
}
__device__ __forceinline__ float bf_hi(unsigned int u) {   // high bf16 of a dword
    return __uint_as_float(u & 0xffff0000u);
}

// ---------------------------------------------------------------------------
// Layer 0: one wave per (direction, batch) chain. Lane j owns hidden unit j.
// gi computed on the fly from x (8-wide input). Writes bf16 l0bf[t][b][dir*64+j]
// and the fp32 t=T-1 row into l0T[b][dir*64+j] (head-precision side-band).
// ---------------------------------------------------------------------------
__global__ void __launch_bounds__(64, 1)
l0_kernel(const float* __restrict__ x,
          const float* __restrict__ Wih_f, const float* __restrict__ Whh_f,
          const float* __restrict__ bih_f, const float* __restrict__ bhh_f,
          const float* __restrict__ Wih_b, const float* __restrict__ Whh_b,
          const float* __restrict__ bih_b, const float* __restrict__ bhh_b,
          ushort_t* __restrict__ l0bf, float* __restrict__ l0T)
{
    const int bid = blockIdx.x;
    const int dir = bid & 1;           // 0 = forward, 1 = backward
    const int b   = bid >> 1;
    const int j   = threadIdx.x;

    const float* __restrict__ Wih = dir ? Wih_b : Wih_f;
    const float* __restrict__ Whh = dir ? Whh_b : Whh_f;
    const float* __restrict__ bih = dir ? bih_b : bih_f;
    const float* __restrict__ bhh = dir ? bhh_b : bhh_f;

    // Per-lane recurrent weight rows (r, z, n) — 192 fp32 in registers.
    v2f wr[32], wz[32], wn[32];
    {
        const v2f* p0 = (const v2f*)(Whh + (size_t)j * H_SZ);
        const v2f* p1 = (const v2f*)(Whh + (size_t)(j + 64) * H_SZ);
        const v2f* p2 = (const v2f*)(Whh + (size_t)(j + 128) * H_SZ);
        #pragma unroll
        for (int k = 0; k < 32; ++k) { wr[k] = p0[k]; wz[k] = p1[k]; wn[k] = p2[k]; }
    }
    // Input weight rows (8 wide each).
    float ur[8], uz[8], un[8];
    #pragma unroll
    for (int i = 0; i < 8; ++i) {
        ur[i] = Wih[(size_t)j * 8 + i];
        uz[i] = Wih[(size_t)(j + 64) * 8 + i];
        un[i] = Wih[(size_t)(j + 128) * 8 + i];
    }
    const float b_rz_r = bih[j] + bhh[j];
    const float b_rz_z = bih[j + 64] + bhh[j + 64];
    const float b_in   = bih[j + 128];
    const float b_hn   = bhh[j + 128];

    __shared__ __align__(16) float hs[H_SZ];
    float h = 0.0f;
    hs[j] = 0.0f;
    __syncthreads();

    const float* __restrict__ xb = x + (size_t)b * T_LEN * 8;
    ushort_t* __restrict__ outp = l0bf + (size_t)b * 128 + dir * 64 + j;

    #pragma unroll 1
    for (int s = 0; s < T_LEN; ++s) {
        const int tt = dir ? (T_LEN - 1 - s) : s;
        const float4* xp = (const float4*)(xb + (size_t)tt * 8);
        const float4 x0 = xp[0];
        const float4 x1 = xp[1];

        // gi = bih + Wih . x  (biases pre-folded where possible)
        float gr = b_rz_r, gz = b_rz_z, gn = b_in;
        gr = fmaf(ur[0], x0.x, gr); gr = fmaf(ur[1], x0.y, gr);
        gr = fmaf(ur[2], x0.z, gr); gr = fmaf(ur[3], x0.w, gr);
        gr = fmaf(ur[4], x1.x, gr); gr = fmaf(ur[5], x1.y, gr);
        gr = fmaf(ur[6], x1.z, gr); gr = fmaf(ur[7], x1.w, gr);
        gz = fmaf(uz[0], x0.x, gz); gz = fmaf(uz[1], x0.y, gz);
        gz = fmaf(uz[2], x0.z, gz); gz = fmaf(uz[3], x0.w, gz);
        gz = fmaf(uz[4], x1.x, gz); gz = fmaf(uz[5], x1.y, gz);
        gz = fmaf(uz[6], x1.z, gz); gz = fmaf(uz[7], x1.w, gz);
        gn = fmaf(un[0], x0.x, gn); gn = fmaf(un[1], x0.y, gn);
        gn = fmaf(un[2], x0.z, gn); gn = fmaf(un[3], x0.w, gn);
        gn = fmaf(un[4], x1.x, gn); gn = fmaf(un[5], x1.y, gn);
        gn = fmaf(un[6], x1.z, gn); gn = fmaf(un[7], x1.w, gn);

        // gh = Whh . h  (h broadcast through LDS)
        v2f ar0 = {0.f,0.f}, ar1 = {0.f,0.f};
        v2f az0 = {0.f,0.f}, az1 = {0.f,0.f};
        v2f an0 = {0.f,0.f}, an1 = {0.f,0.f};
        const float4* hs4 = (const float4*)hs;
        #pragma unroll
        for (int k4 = 0; k4 < 16; ++k4) {
            const float4 hv = hs4[k4];
            const v2f h0 = {hv.x, hv.y};
            const v2f h1 = {hv.z, hv.w};
            ar0 = v2fma(wr[2*k4],   h0, ar0);
            ar1 = v2fma(wr[2*k4+1], h1, ar1);
            az0 = v2fma(wz[2*k4],   h0, az0);
            az1 = v2fma(wz[2*k4+1], h1, az1);
            an0 = v2fma(wn[2*k4],   h0, an0);
            an1 = v2fma(wn[2*k4+1], h1, an1);
        }
        const float hr = (ar0.x + ar0.y) + (ar1.x + ar1.y);
        const float hz = (az0.x + az0.y) + (az1.x + az1.y);
        const float hn = (an0.x + an0.y) + (an1.x + an1.y) + b_hn;

        const float r = sigmf(gr + hr);
        const float z = sigmf(gz + hz);
        const float n = tanhf_fast(gn + r * hn);
        h = fmaf(z, h - n, n);          // (1-z)*n + z*h

        hs[j] = h;                       // single wave: program-order LDS
        outp[(size_t)tt * (B_SZ * 128)] = f2bf(h);
        if (tt == T_LEN - 1)
            l0T[(size_t)b * 128 + dir * 64 + j] = h;
        __syncthreads();
    }
}

// ---------------------------------------------------------------------------
// Layer 1 forward: 3 waves per batch. Wave 0 = recurrent consumer,
// waves 1..2 = gi producers (each a 64-wide K-slice of Wih_l1_f over the
// bf16 layer-0 output), double-buffered gi partials in LDS, one barrier/step.
// Only the final hidden state is stored.
// ---------------------------------------------------------------------------
__global__ void __launch_bounds__(192, 1)
l1_kernel(const ushort_t* __restrict__ l0bf,
          const float* __restrict__ Wih, const float* __restrict__ Whh,
          const float* __restrict__ bih, const float* __restrict__ bhh,
          float* __restrict__ hf)
{
    const int b  = blockIdx.x;
    const int wv = threadIdx.x >> 6;   // 0 consumer, 1..2 producers
    const int j  = threadIdx.x & 63;

    __shared__ __align__(16) float hs[H_SZ];
    __shared__ __align__(16) float gip[2][2][192];

    // Unified per-lane weight block: consumer holds Whh rows, producers hold
    // Wih row K-slices. Same register footprint (3 x 64 fp32).
    v2f wA[32], wB[32], wC[32];
    if (wv == 0) {
        const v2f* p0 = (const v2f*)(Whh + (size_t)j * H_SZ);
        const v2f* p1 = (const v2f*)(Whh + (size_t)(j + 64) * H_SZ);
        const v2f* p2 = (const v2f*)(Whh + (size_t)(j + 128) * H_SZ);
        #pragma unroll
        for (int k = 0; k < 32; ++k) { wA[k] = p0[k]; wB[k] = p1[k]; wC[k] = p2[k]; }
        hs[j] = 0.0f;
    } else {
        const int kb = (wv - 1) * 64;
        const v2f* p0 = (const v2f*)(Wih + (size_t)j * 128 + kb);
        const v2f* p1 = (const v2f*)(Wih + (size_t)(j + 64) * 128 + kb);
        const v2f* p2 = (const v2f*)(Wih + (size_t)(j + 128) * 128 + kb);
        #pragma unroll
        for (int k = 0; k < 32; ++k) { wA[k] = p0[k]; wB[k] = p1[k]; wC[k] = p2[k]; }
    }
    const float b_rz_r = bih[j] + bhh[j];
    const float b_rz_z = bih[j + 64] + bhh[j + 64];
    const float b_in   = bih[j + 128];
    const float b_hn   = bhh[j + 128];

    float h = 0.0f;

    // producer: gi partial over 64-wide bf16 K-slice of l0 output row t
    auto produce = [&](int tp) {
        const int bf = tp & 1;
        const uint4* ap = (const uint4*)(l0bf + ((size_t)tp * B_SZ + b) * 128 + (wv - 1) * 64);
        v2f aA0 = {0.f,0.f}, aA1 = {0.f,0.f};
        v2f aB0 = {0.f,0.f}, aB1 = {0.f,0.f};
        v2f aC0 = {0.f,0.f}, aC1 = {0.f,0.f};
        #pragma unroll
        for (int q = 0; q < 8; ++q) {          // 8 x uint4 = 64 bf16
            const uint4 u4 = ap[q];
            const v2f a0 = {bf_lo(u4.x), bf_hi(u4.x)};
            const v2f a1 = {bf_lo(u4.y), bf_hi(u4.y)};
            const v2f a2 = {bf_lo(u4.z), bf_hi(u4.z)};
            const v2f a3 = {bf_lo(u4.w), bf_hi(u4.w)};
            aA0 = v2fma(wA[4*q],   a0, aA0);
            aA1 = v2fma(wA[4*q+1], a1, aA1);
            aA0 = v2fma(wA[4*q+2], a2, aA0);
            aA1 = v2fma(wA[4*q+3], a3, aA1);
            aB0 = v2fma(wB[4*q],   a0, aB0);
            aB1 = v2fma(wB[4*q+1], a1, aB1);
            aB0 = v2fma(wB[4*q+2], a2, aB0);
            aB1 = v2fma(wB[4*q+3], a3, aB1);
            aC0 = v2fma(wC[4*q],   a0, aC0);
            aC1 = v2fma(wC[4*q+1], a1, aC1);
            aC0 = v2fma(wC[4*q+2], a2, aC0);
            aC1 = v2fma(wC[4*q+3], a3, aC1);
        }
        gip[bf][wv - 1][j]       = (aA0.x + aA0.y) + (aA1.x + aA1.y);
        gip[bf][wv - 1][j + 64]  = (aB0.x + aB0.y) + (aB1.x + aB1.y);
        gip[bf][wv - 1][j + 128] = (aC0.x + aC0.y) + (aC1.x + aC1.y);
    };

    // prologue: fill gi for t = 0
    if (wv > 0) produce(0);
    __syncthreads();

    #pragma unroll 1
    for (int t = 0; t < T_LEN; ++t) {
        if (wv == 0) {
            const int bf = t & 1;
            float gr = gip[bf][0][j]       + gip[bf][1][j]       + b_rz_r;
            float gz = gip[bf][0][j + 64]  + gip[bf][1][j + 64]  + b_rz_z;
            float gn = gip[bf][0][j + 128] + gip[bf][1][j + 128] + b_in;

            v2f ar0 = {0.f,0.f}, ar1 = {0.f,0.f};
            v2f az0 = {0.f,0.f}, az1 = {0.f,0.f};
            v2f an0 = {0.f,0.f}, an1 = {0.f,0.f};
            const float4* hs4 = (const float4*)hs;
            #pragma unroll
            for (int k4 = 0; k4 < 16; ++k4) {
                const float4 hv = hs4[k4];
                const v2f h0 = {hv.x, hv.y};
                const v2f h1 = {hv.z, hv.w};
                ar0 = v2fma(wA[2*k4],   h0, ar0);
                ar1 = v2fma(wA[2*k4+1], h1, ar1);
                az0 = v2fma(wB[2*k4],   h0, az0);
                az1 = v2fma(wB[2*k4+1], h1, az1);
                an0 = v2fma(wC[2*k4],   h0, an0);
                an1 = v2fma(wC[2*k4+1], h1, an1);
            }
            const float hr = (ar0.x + ar0.y) + (ar1.x + ar1.y);
            const float hz = (az0.x + az0.y) + (az1.x + az1.y);
            const float hn = (an0.x + an0.y) + (an1.x + an1.y) + b_hn;

            const float r = sigmf(gr + hr);
            const float z = sigmf(gz + hz);
            const float n = tanhf_fast(gn + r * hn);
            h = fmaf(z, h - n, n);
            hs[j] = h;
        } else if (t + 1 < T_LEN) {
            produce(t + 1);
        }
        __syncthreads();
    }

    if (wv == 0) hf[(size_t)b * 64 + j] = h;
}

// ---------------------------------------------------------------------------
// Head: per batch — single backward-l1 GRU step (h0 = 0, so gh = bhh),
// concat(last_fwd, ob), FC 128->128 ReLU, FC 128->24.
// Uses the fp32 l0T side-band row for full precision.
// ---------------------------------------------------------------------------
__global__ void __launch_bounds__(192)
head_kernel(const float* __restrict__ l0T,
            const float* __restrict__ Wih_b1, const float* __restrict__ bih_b1,
            const float* __restrict__ bhh_b1,
            const float* __restrict__ hf,
            const float* __restrict__ W1, const float* __restrict__ b1,
            const float* __restrict__ W2, const float* __restrict__ b2,
            float* __restrict__ out)
{
    const int b   = blockIdx.x;
    const int tid = threadIdx.x;

    __shared__ __align__(16) float a_s[128];
    __shared__ __align__(16) float gi_s[192];
    __shared__ __align__(16) float last_s[128];
    __shared__ __align__(16) float hid_s[128];

    if (tid < 128)
        a_s[tid] = l0T[(size_t)b * 128 + tid];
    __syncthreads();

    // gi[g] = bih_b1[g] + Wih_b1[g,:] . a   (g = tid, 192 threads)
    {
        float acc = bih_b1[tid];
        const float4* wrow = (const float4*)(Wih_b1 + (size_t)tid * 128);
        const float4* av4  = (const float4*)a_s;
        #pragma unroll
        for (int k4 = 0; k4 < 32; ++k4) {
            const float4 w  = wrow[k4];
            const float4 av = av4[k4];
            acc = fmaf(w.x, av.x, acc); acc = fmaf(w.y, av.y, acc);
            acc = fmaf(w.z, av.z, acc); acc = fmaf(w.w, av.w, acc);
        }
        gi_s[tid] = acc;
    }
    __syncthreads();

    if (tid < 64) {
        const float r = sigmf(gi_s[tid]      + bhh_b1[tid]);
        const float z = sigmf(gi_s[tid + 64] + bhh_b1[tid + 64]);
        const float n = tanhf_fast(gi_s[tid + 128] + r * bhh_b1[tid + 128]);
        last_s[64 + tid] = (1.0f - z) * n;      // h0 = 0 => (1-z)*n
        last_s[tid]      = hf[(size_t)b * 64 + tid];
    }
    __syncthreads();

    if (tid < 128) {
        float acc = b1[tid];
        const float4* wrow = (const float4*)(W1 + (size_t)tid * 128);
        const float4* lv4  = (const float4*)last_s;
        #pragma unroll
        for (int k4 = 0; k4 < 32; ++k4) {
            const float4 w = wrow[k4];
            const float4 l = lv4[k4];
            acc = fmaf(w.x, l.x, acc); acc = fmaf(w.y, l.y, acc);
            acc = fmaf(w.z, l.z, acc); acc = fmaf(w.w, l.w, acc);
        }
        hid_s[tid] = fmaxf(acc, 0.0f);
    }
    __syncthreads();

    if (tid < 24) {
        float acc = b2[tid];
        const float4* wrow = (const float4*)(W2 + (size_t)tid * 128);
        const float4* hv4  = (const float4*)hid_s;
        #pragma unroll
        for (int k4 = 0; k4 < 32; ++k4) {
            const float4 w = wrow[k4];
            const float4 hv = hv4[k4];
            acc = fmaf(w.x, hv.x, acc); acc = fmaf(w.y, hv.y, acc);
            acc = fmaf(w.z, hv.z, acc); acc = fmaf(w.w, hv.w, acc);
        }
        out[(size_t)b * 24 + tid] = acc;
    }
}

extern "C" void kernel_launch(void* const* d_in, const int* in_sizes, int n_in,
                              void* d_out, int out_size, void* d_ws, size_t ws_size,
                              hipStream_t stream)
{
    const float* x        = (const float*)d_in[0];
    const float* Wih_l0_f = (const float*)d_in[1];
    const float* Whh_l0_f = (const float*)d_in[2];
    const float* bih_l0_f = (const float*)d_in[3];
    const float* bhh_l0_f = (const float*)d_in[4];
    const float* Wih_l0_b = (const float*)d_in[5];
    const float* Whh_l0_b = (const float*)d_in[6];
    const float* bih_l0_b = (const float*)d_in[7];
    const float* bhh_l0_b = (const float*)d_in[8];
    const float* Wih_l1_f = (const float*)d_in[9];
    const float* Whh_l1_f = (const float*)d_in[10];
    const float* bih_l1_f = (const float*)d_in[11];
    const float* bhh_l1_f = (const float*)d_in[12];
    const float* Wih_l1_b = (const float*)d_in[13];
    /* Whh_l1_b (d_in[14]) unused: backward-l1 step starts from h0 = 0 */
    const float* bih_l1_b = (const float*)d_in[15];
    const float* bhh_l1_b = (const float*)d_in[16];
    const float* W1 = (const float*)d_in[17];
    const float* b1 = (const float*)d_in[18];
    const float* W2 = (const float*)d_in[19];
    const float* b2 = (const float*)d_in[20];

    // Workspace layout (total ~128.2 MiB):
    //   [0, 128Mi)          bf16 l0bf[T][B][128]
    //   [+0, +128KiB)       fp32 l0T[B][128]   (t = T-1 row, head precision)
    //   [+128KiB, +192KiB)  fp32 hf[B][64]
    ushort_t* l0bf = (ushort_t*)d_ws;
    float*    l0T  = (float*)((char*)d_ws + (size_t)T_LEN * B_SZ * 128 * sizeof(ushort_t));
    float*    hf   = l0T + (size_t)B_SZ * 128;

    hipLaunchKernelGGL(l0_kernel, dim3(2 * B_SZ), dim3(64), 0, stream,
                       x, Wih_l0_f, Whh_l0_f, bih_l0_f, bhh_l0_f,
                       Wih_l0_b, Whh_l0_b, bih_l0_b, bhh_l0_b, l0bf, l0T);

    hipLaunchKernelGGL(l1_kernel, dim3(B_SZ), dim3(192), 0, stream,
                       l0bf, Wih_l1_f, Whh_l1_f, bih_l1_f, bhh_l1_f, hf);

    hipLaunchKernelGGL(head_kernel, dim3(B_SZ), dim3(192), 0, stream,
                       l0T, Wih_l1_b, bih_l1_b, bhh_l1_b, hf,
                       W1, b1, W2, b2, (float*)d_out);
}